// Round 14
// baseline (43.481 us; speedup 1.0000x reference)
//
#include <hip/hip_runtime.h>
#include <cstddef>
#include <cstdint>

#define BDIM 4
#define HH   64
#define WW   64
#define NG   4
#define GD   64
#define HWSZ 4096
#define NTOT 16384          // BDIM*HWSZ
#define CIN  256

typedef __attribute__((ext_vector_type(4))) float f32x4;
typedef _Float16 f16x4_t __attribute__((ext_vector_type(4)));
typedef _Float16 f16x8_t __attribute__((ext_vector_type(8)));

// ---------- fused QKV GEMM: fp32 in, fp16 MFMA, fp16 blocked out ----------
// D[768 x 16384] = W[768 x 256] * x[256 x 16384]. 128x128 tile, 4 waves,
// BK=32, 8 K-steps, 2-deep double buffer, issue-early / write-late, NO
// global_load_lds (no vmcnt-drain at barriers). Both operands reg-staged
// to fp16 LDS:
//   A (W): 4x float4 coalesced + cvt -> Ap[m][32k]; slot ^= (m>>1)&3.
//   B (x): 16 k-strided dwords + cvt -> Bs[px][32k]; slot ^= px&3 (R12).
// Frag reads: single b128 each. LDS 32 KB, 3 blocks/CU.
__global__ __launch_bounds__(256, 3) void qkv_gemm_kernel(
    const float* __restrict__ x,
    const float* __restrict__ wq, const float* __restrict__ bq,
    const float* __restrict__ wk, const float* __restrict__ bk,
    const float* __restrict__ wv, const float* __restrict__ bv,
    _Float16* __restrict__ qh, _Float16* __restrict__ kh,
    _Float16* __restrict__ vh)
{
    __shared__ _Float16 Ap[2][128 * 32];   // 2 x 8 KB fp16
    __shared__ _Float16 Bs[2][128 * 32];   // 2 x 8 KB fp16

    const int t  = threadIdx.x;
    const int bx = blockIdx.x;
    const int u  = (bx & 7) * 96 + (bx >> 3);   // XCD-chunked (768 = 8*96)
    const int mt = u % 6;                       // consecutive u share nt (x panel)
    const int nt = u / 6;                       // 0..127

    const int l     = t & 63;
    const int wid   = t >> 6;
    const int wm    = wid >> 1, wn = wid & 1;
    const int lrow  = l & 15;
    const int grp   = l >> 4;                   // koct 0..3
    const int lrow4 = grp * 4;

    const float* wsel = (mt < 2) ? wq : (mt < 4) ? wk : wv;
    const float* bsel = (mt < 2) ? bq : (mt < 4) ? bk : bv;
    _Float16*    osel = (mt < 2) ? qh : (mt < 4) ? kh : vh;
    const int    mtl  = mt & 1;

    const int bi  = nt >> 5;
    const int px0 = (nt & 31) * 128;

    // acc init with bias
    f32x4 acc[4][4];
    #pragma unroll
    for (int mi = 0; mi < 4; ++mi) {
        const f32x4 bb = *(const f32x4*)&bsel[mtl * 128 + wm * 64 + mi * 16 + lrow4];
        #pragma unroll
        for (int ni = 0; ni < 4; ++ni) acc[mi][ni] = bb;
    }

    // ---- A staging: thread -> (row smA = t>>1, k-half khA = t&1) ----
    const int smA = t >> 1;
    const int khA = t & 1;
    const float* wrow = wsel + (size_t)(mtl * 128 + smA) * CIN + khA * 16;
    const int aswz = (smA >> 1) & 3;
    const int aw0  = smA * 32 + (((khA * 2)     ^ aswz) * 8);
    const int aw1  = smA * 32 + (((khA * 2 + 1) ^ aswz) * 8);

    // ---- B staging: px = t&127, kocts {t>>7, (t>>7)+2} (R12 pattern) ----
    const int spx  = t & 127;
    const int sko0 = t >> 7;                 // 0..1
    const float* xbp = x + (size_t)bi * CIN * HWSZ + px0 + spx;
    const int bw0 = spx * 32 + ((sko0       ^ (spx & 3)) * 8);
    const int bw1 = spx * 32 + (((sko0 + 2) ^ (spx & 3)) * 8);

    // ---- prologue: stage kt=0 into buf 0 ----
    {
        float4 a4[4];
        #pragma unroll
        for (int q4 = 0; q4 < 4; ++q4) a4[q4] = *(const float4*)(wrow + q4 * 4);
        float r0[8], r1[8];
        #pragma unroll
        for (int j = 0; j < 8; ++j) r0[j] = xbp[(size_t)(sko0 * 8 + j) * HWSZ];
        #pragma unroll
        for (int j = 0; j < 8; ++j) r1[j] = xbp[(size_t)((sko0 + 2) * 8 + j) * HWSZ];
        f16x8_t wa0, wa1, w0, w1;
        const float* af4 = (const float*)a4;
        #pragma unroll
        for (int j = 0; j < 8; ++j) { wa0[j] = (_Float16)af4[j]; wa1[j] = (_Float16)af4[8 + j]; }
        #pragma unroll
        for (int j = 0; j < 8; ++j) { w0[j] = (_Float16)r0[j]; w1[j] = (_Float16)r1[j]; }
        *(f16x8_t*)&Ap[0][aw0] = wa0;
        *(f16x8_t*)&Ap[0][aw1] = wa1;
        *(f16x8_t*)&Bs[0][bw0] = w0;
        *(f16x8_t*)&Bs[0][bw1] = w1;
        __syncthreads();
    }

    for (int kt = 0; kt < 8; ++kt) {
        const int cur = kt & 1, nxt = cur ^ 1;

        // issue next-step loads early (hide under frag reads + MFMA)
        float4 a4[4];
        float r0[8], r1[8];
        if (kt < 7) {
            const int kb = (kt + 1) * 32;
            #pragma unroll
            for (int q4 = 0; q4 < 4; ++q4) a4[q4] = *(const float4*)(wrow + kb + q4 * 4);
            #pragma unroll
            for (int j = 0; j < 8; ++j) r0[j] = xbp[(size_t)(kb + sko0 * 8 + j) * HWSZ];
            #pragma unroll
            for (int j = 0; j < 8; ++j) r1[j] = xbp[(size_t)(kb + (sko0 + 2) * 8 + j) * HWSZ];
        }

        // A fragments: single swizzled fp16 b128 read per mi
        f16x8_t af[4], bf[4];
        #pragma unroll
        for (int mi = 0; mi < 4; ++mi) {
            const int m = wm * 64 + mi * 16 + lrow;
            af[mi] = *(const f16x8_t*)&Ap[cur][m * 32 + ((grp ^ ((m >> 1) & 3)) * 8)];
        }
        // B fragments: single swizzled b128 read per ni
        #pragma unroll
        for (int ni = 0; ni < 4; ++ni) {
            const int px = wn * 64 + ni * 16 + lrow;
            bf[ni] = *(const f16x8_t*)&Bs[cur][px * 32 + ((grp ^ (px & 3)) * 8)];
        }
        #pragma unroll
        for (int mi = 0; mi < 4; ++mi)
            #pragma unroll
            for (int ni = 0; ni < 4; ++ni)
                acc[mi][ni] = __builtin_amdgcn_mfma_f32_16x16x32_f16(
                    af[mi], bf[ni], acc[mi][ni], 0, 0, 0);

        // write-late: convert + store next tiles
        if (kt < 7) {
            f16x8_t wa0, wa1, w0, w1;
            const float* af4 = (const float*)a4;
            #pragma unroll
            for (int j = 0; j < 8; ++j) { wa0[j] = (_Float16)af4[j]; wa1[j] = (_Float16)af4[8 + j]; }
            #pragma unroll
            for (int j = 0; j < 8; ++j) { w0[j] = (_Float16)r0[j]; w1[j] = (_Float16)r1[j]; }
            *(f16x8_t*)&Ap[nxt][aw0] = wa0;
            *(f16x8_t*)&Ap[nxt][aw1] = wa1;
            *(f16x8_t*)&Bs[nxt][bw0] = w0;
            *(f16x8_t*)&Bs[nxt][bw1] = w1;
        }
        __syncthreads();
    }

    // epilogue: D row (m) = grp*4+reg, col (n) = l&15 — blocked fp16 stores
    #pragma unroll
    for (int ni = 0; ni < 4; ++ni) {
        const size_t ng = (size_t)(nt * 128 + wn * 64 + ni * 16 + lrow);
        #pragma unroll
        for (int mi = 0; mi < 4; ++mi) {
            f16x4_t hv;
            #pragma unroll
            for (int j = 0; j < 4; ++j) hv[j] = (_Float16)acc[mi][ni][j];
            const int chunk = mtl * 8 + wm * 4 + mi;     // 0..15
            *(f16x4_t*)&osel[((size_t)chunk * NTOT + ng) * 16 + lrow4] = hv;
        }
    }
}

// ---------- local grouped attention: q,k,v fp16 blocked; fp32 math ----------
__global__ __launch_bounds__(256) void loc_attn_kernel(
    const _Float16* __restrict__ qh, const _Float16* __restrict__ kh,
    const _Float16* __restrict__ vh, float* __restrict__ out)
{
    const int t   = threadIdx.x;
    const int bx0 = blockIdx.x;
    const int bx  = (bx0 & 7) * 128 + (bx0 >> 3);
    const int h = bx & 63;
    const int g = (bx >> 6) & 3;
    const int b = bx >> 8;

    const int wl  = t & 15;
    const int c   = (t >> 4) & 3;
    const int wid = t >> 6;
    const int w   = wid * 16 + wl;

    const int ck = g * 4 + c;                    // chunk index 0..15
    const size_t n = (size_t)b * HWSZ + h * 64 + w;

    float qf[16];
    {
        const _Float16* qp = &qh[((size_t)ck * NTOT + n) * 16];
        const f16x8_t q0 = *(const f16x8_t*)qp;
        const f16x8_t q1 = *(const f16x8_t*)(qp + 8);
        #pragma unroll
        for (int j = 0; j < 8; ++j) { qf[j] = (float)q0[j]; qf[8 + j] = (float)q1[j]; }
    }

    float logit[9];
    #pragma unroll
    for (int p = 0; p < 9; ++p) {
        const int dh = p / 3 - 1, dw = p % 3 - 1;
        const int hh = h + dh, ww2 = w + dw;
        float part = 0.f;
        if (hh >= 0 && hh < HH && ww2 >= 0 && ww2 < WW) {
            const size_t nn = (size_t)b * HWSZ + hh * 64 + ww2;
            const _Float16* kp = &kh[((size_t)ck * NTOT + nn) * 16];
            const f16x8_t k0 = *(const f16x8_t*)kp;
            const f16x8_t k1 = *(const f16x8_t*)(kp + 8);
            #pragma unroll
            for (int j = 0; j < 8; ++j)
                part += qf[j] * (float)k0[j] + qf[8 + j] * (float)k1[j];
        }
        part += __shfl_xor(part, 16, 64);
        part += __shfl_xor(part, 32, 64);
        logit[p] = part;
    }

    float mx = logit[0];
    #pragma unroll
    for (int p = 1; p < 9; ++p) mx = fmaxf(mx, logit[p]);
    float a[9];
    float s = 0.f;
    #pragma unroll
    for (int p = 0; p < 9; ++p) { a[p] = __expf(logit[p] - mx); s += a[p]; }
    const float inv = 1.f / s;
    #pragma unroll
    for (int p = 0; p < 9; ++p) a[p] *= inv;

    float acc[16];
    #pragma unroll
    for (int dd = 0; dd < 16; ++dd) acc[dd] = 0.f;
    #pragma unroll
    for (int p = 0; p < 9; ++p) {
        const int dh = p / 3 - 1, dw = p % 3 - 1;
        const int hh = h + dh, ww2 = w + dw;
        if (hh < 0 || hh >= HH || ww2 < 0 || ww2 >= WW) continue;
        const size_t nn = (size_t)b * HWSZ + hh * 64 + ww2;
        const _Float16* vp = &vh[((size_t)ck * NTOT + nn) * 16];
        const f16x8_t v0 = *(const f16x8_t*)vp;
        const f16x8_t v1 = *(const f16x8_t*)(vp + 8);
        const float ap = a[p];
        #pragma unroll
        for (int j = 0; j < 8; ++j) {
            acc[j]     += ap * (float)v0[j];
            acc[8 + j] += ap * (float)v1[j];
        }
    }

    const int obase = b * 256 + g * 64 + c * 16;
    const int off = h * 64 + w;
    #pragma unroll
    for (int dd = 0; dd < 16; ++dd)
        out[(size_t)(obase + dd) * HWSZ + off] = acc[dd];
}

extern "C" void kernel_launch(void* const* d_in, const int* in_sizes, int n_in,
                              void* d_out, int out_size, void* d_ws, size_t ws_size,
                              hipStream_t stream) {
    const float* x  = (const float*)d_in[0];
    const float* wq = (const float*)d_in[1];
    const float* bq = (const float*)d_in[2];
    const float* wk = (const float*)d_in[3];
    const float* bk = (const float*)d_in[4];
    const float* wv = (const float*)d_in[5];
    const float* bv = (const float*)d_in[6];
    float* out = (float*)d_out;

    char* ws = (char*)d_ws;
    _Float16* qh = (_Float16*)ws;                      //  8.39 MB
    _Float16* kh = (_Float16*)(ws + 8388608);          //  8.39 MB
    _Float16* vh = (_Float16*)(ws + 16777216);         //  8.39 MB

    qkv_gemm_kernel<<<dim3(768), 256, 0, stream>>>(x, wq, bq, wk, bk, wv, bv,
                                                   qh, kh, vh);
    loc_attn_kernel<<<dim3(1024), 256, 0, stream>>>(qh, kh, vh, out);
}

// Round 15
// 37.333 us; speedup vs baseline: 1.1647x; 1.1647x over previous
//
#include <hip/hip_runtime.h>
#include <cstddef>
#include <cstdint>

#define BDIM 4
#define HH   64
#define WW   64
#define NG   4
#define GD   64
#define HWSZ 4096
#define NTOT 16384          // BDIM*HWSZ
#define CIN  256

typedef __attribute__((ext_vector_type(4))) float f32x4;
typedef _Float16 f16x4_t __attribute__((ext_vector_type(4)));
typedef _Float16 f16x8_t __attribute__((ext_vector_type(8)));

__device__ __forceinline__ void lds_load16(const void* g, void* l) {
    __builtin_amdgcn_global_load_lds(
        (const __attribute__((address_space(1))) unsigned int*)g,
        (__attribute__((address_space(3))) unsigned int*)l, 16, 0, 0);
}

// ---------- fused QKV GEMM (R12 data path, 512 threads / 8 waves) ----------
// D[768 x 16384] = W[768 x 256] * x[256 x 16384]. 128x128 tile, 8 waves
// (2m x 4n), BK=32, 8 K-steps, 2-deep double buffer.
//   A (W): gload_lds fp32, source swizzle kb^=(m&7); frags 2x f32x4 + cvt.
//   B (x): reg-staged fp16, slot ^= px&3 both sides; frags 1x b128.
// 24 waves/CU (vs R12's 12) to hide x-load latency. Blocked fp16 outputs.
__global__ __launch_bounds__(512, 4) void qkv_gemm_kernel(
    const float* __restrict__ x,
    const float* __restrict__ wq, const float* __restrict__ bq,
    const float* __restrict__ wk, const float* __restrict__ bk,
    const float* __restrict__ wv, const float* __restrict__ bv,
    _Float16* __restrict__ qh, _Float16* __restrict__ kh,
    _Float16* __restrict__ vh)
{
    __shared__ float    As[2][128 * 32];   // 2 x 16 KB fp32
    __shared__ _Float16 Bs[2][128 * 32];   // 2 x  8 KB fp16

    const int t  = threadIdx.x;
    const int bx = blockIdx.x;
    const int u  = (bx & 7) * 96 + (bx >> 3);   // XCD-chunked (768 = 8*96)
    const int mt = u % 6;                       // consecutive u share nt (x panel)
    const int nt = u / 6;                       // 0..127

    const int l     = t & 63;
    const int wid   = t >> 6;                   // 0..7
    const int wm    = wid >> 2, wn = wid & 3;   // 2m x 4n
    const int lrow  = l & 15;
    const int grp   = l >> 4;                   // koct 0..3
    const int lrow4 = grp * 4;

    const float* wsel = (mt < 2) ? wq : (mt < 4) ? wk : wv;
    const float* bsel = (mt < 2) ? bq : (mt < 4) ? bk : bv;
    _Float16*    osel = (mt < 2) ? qh : (mt < 4) ? kh : vh;
    const int    mtl  = mt & 1;

    const int bi  = nt >> 5;
    const int px0 = (nt & 31) * 128;

    // acc init with bias
    f32x4 acc[4][2];
    #pragma unroll
    for (int mi = 0; mi < 4; ++mi) {
        const f32x4 bb = *(const f32x4*)&bsel[mtl * 128 + wm * 64 + mi * 16 + lrow4];
        acc[mi][0] = bb; acc[mi][1] = bb;
    }

    // ---- A staging sources (2 x 16B gload_lds per thread per step) ----
    const float* asrc[2];
    #pragma unroll
    for (int i = 0; i < 2; ++i) {
        const int w16 = i * 512 + t;
        const int m  = w16 >> 3;
        const int kb = w16 & 7;
        asrc[i] = wsel + (size_t)(mtl * 128 + m) * CIN + ((kb ^ (m & 7)) * 4);
    }

    // ---- B staging: px = t&127, koct = t>>7 (8 dwords per thread) ----
    const int spx = t & 127;
    const int sko = t >> 7;                  // 0..3
    const float* xbp = x + (size_t)bi * CIN * HWSZ + px0 + spx;
    const int bw = spx * 32 + ((sko ^ (spx & 3)) * 8);

    // ---- prologue: stage kt=0 into buf 0 ----
    {
        #pragma unroll
        for (int i = 0; i < 2; ++i)
            lds_load16(asrc[i], &As[0][(i * 512 + t) * 4]);
        float r[8];
        #pragma unroll
        for (int j = 0; j < 8; ++j) r[j] = xbp[(size_t)(sko * 8 + j) * HWSZ];
        f16x8_t w8;
        #pragma unroll
        for (int j = 0; j < 8; ++j) w8[j] = (_Float16)r[j];
        *(f16x8_t*)&Bs[0][bw] = w8;
        __syncthreads();
    }

    for (int kt = 0; kt < 8; ++kt) {
        const int cur = kt & 1, nxt = cur ^ 1;

        // issue next-step loads early
        float r[8];
        if (kt < 7) {
            const int kb = (kt + 1) * 32;
            #pragma unroll
            for (int i = 0; i < 2; ++i)
                lds_load16(asrc[i] + kb, &As[nxt][(i * 512 + t) * 4]);
            #pragma unroll
            for (int j = 0; j < 8; ++j) r[j] = xbp[(size_t)(kb + sko * 8 + j) * HWSZ];
        }

        // A fragments: 2 swizzled b128 fp32 reads + cvt
        f16x8_t af[4], bf[2];
        #pragma unroll
        for (int mi = 0; mi < 4; ++mi) {
            const int m = wm * 64 + mi * 16 + lrow;
            const int s = m & 7;
            const f32x4 a0 = *(const f32x4*)&As[cur][m * 32 + ((2 * grp) ^ s) * 4];
            const f32x4 a1 = *(const f32x4*)&As[cur][m * 32 + ((2 * grp + 1) ^ s) * 4];
            f16x8_t f;
            #pragma unroll
            for (int j = 0; j < 4; ++j) { f[j] = (_Float16)a0[j]; f[4 + j] = (_Float16)a1[j]; }
            af[mi] = f;
        }
        // B fragments: single swizzled b128 read per ni
        #pragma unroll
        for (int ni = 0; ni < 2; ++ni) {
            const int px = wn * 32 + ni * 16 + lrow;
            bf[ni] = *(const f16x8_t*)&Bs[cur][px * 32 + ((grp ^ (px & 3)) * 8)];
        }
        #pragma unroll
        for (int mi = 0; mi < 4; ++mi)
            #pragma unroll
            for (int ni = 0; ni < 2; ++ni)
                acc[mi][ni] = __builtin_amdgcn_mfma_f32_16x16x32_f16(
                    af[mi], bf[ni], acc[mi][ni], 0, 0, 0);

        // write-late: convert + store next B tile
        if (kt < 7) {
            f16x8_t w8;
            #pragma unroll
            for (int j = 0; j < 8; ++j) w8[j] = (_Float16)r[j];
            *(f16x8_t*)&Bs[nxt][bw] = w8;
        }
        __syncthreads();
    }

    // epilogue: blocked fp16 stores
    #pragma unroll
    for (int ni = 0; ni < 2; ++ni) {
        const size_t ng = (size_t)(nt * 128 + wn * 32 + ni * 16 + lrow);
        #pragma unroll
        for (int mi = 0; mi < 4; ++mi) {
            f16x4_t hv;
            #pragma unroll
            for (int j = 0; j < 4; ++j) hv[j] = (_Float16)acc[mi][ni][j];
            const int chunk = mtl * 8 + wm * 4 + mi;     // 0..15
            *(f16x4_t*)&osel[((size_t)chunk * NTOT + ng) * 16 + lrow4] = hv;
        }
    }
}

// ---------- local grouped attention: q,k,v fp16 blocked; fp32 math ----------
__global__ __launch_bounds__(256) void loc_attn_kernel(
    const _Float16* __restrict__ qh, const _Float16* __restrict__ kh,
    const _Float16* __restrict__ vh, float* __restrict__ out)
{
    const int t   = threadIdx.x;
    const int bx0 = blockIdx.x;
    const int bx  = (bx0 & 7) * 128 + (bx0 >> 3);
    const int h = bx & 63;
    const int g = (bx >> 6) & 3;
    const int b = bx >> 8;

    const int wl  = t & 15;
    const int c   = (t >> 4) & 3;
    const int wid = t >> 6;
    const int w   = wid * 16 + wl;

    const int ck = g * 4 + c;                    // chunk index 0..15
    const size_t n = (size_t)b * HWSZ + h * 64 + w;

    float qf[16];
    {
        const _Float16* qp = &qh[((size_t)ck * NTOT + n) * 16];
        const f16x8_t q0 = *(const f16x8_t*)qp;
        const f16x8_t q1 = *(const f16x8_t*)(qp + 8);
        #pragma unroll
        for (int j = 0; j < 8; ++j) { qf[j] = (float)q0[j]; qf[8 + j] = (float)q1[j]; }
    }

    float logit[9];
    #pragma unroll
    for (int p = 0; p < 9; ++p) {
        const int dh = p / 3 - 1, dw = p % 3 - 1;
        const int hh = h + dh, ww2 = w + dw;
        float part = 0.f;
        if (hh >= 0 && hh < HH && ww2 >= 0 && ww2 < WW) {
            const size_t nn = (size_t)b * HWSZ + hh * 64 + ww2;
            const _Float16* kp = &kh[((size_t)ck * NTOT + nn) * 16];
            const f16x8_t k0 = *(const f16x8_t*)kp;
            const f16x8_t k1 = *(const f16x8_t*)(kp + 8);
            #pragma unroll
            for (int j = 0; j < 8; ++j)
                part += qf[j] * (float)k0[j] + qf[8 + j] * (float)k1[j];
        }
        part += __shfl_xor(part, 16, 64);
        part += __shfl_xor(part, 32, 64);
        logit[p] = part;
    }

    float mx = logit[0];
    #pragma unroll
    for (int p = 1; p < 9; ++p) mx = fmaxf(mx, logit[p]);
    float a[9];
    float s = 0.f;
    #pragma unroll
    for (int p = 0; p < 9; ++p) { a[p] = __expf(logit[p] - mx); s += a[p]; }
    const float inv = 1.f / s;
    #pragma unroll
    for (int p = 0; p < 9; ++p) a[p] *= inv;

    float acc[16];
    #pragma unroll
    for (int dd = 0; dd < 16; ++dd) acc[dd] = 0.f;
    #pragma unroll
    for (int p = 0; p < 9; ++p) {
        const int dh = p / 3 - 1, dw = p % 3 - 1;
        const int hh = h + dh, ww2 = w + dw;
        if (hh < 0 || hh >= HH || ww2 < 0 || ww2 >= WW) continue;
        const size_t nn = (size_t)b * HWSZ + hh * 64 + ww2;
        const _Float16* vp = &vh[((size_t)ck * NTOT + nn) * 16];
        const f16x8_t v0 = *(const f16x8_t*)vp;
        const f16x8_t v1 = *(const f16x8_t*)(vp + 8);
        const float ap = a[p];
        #pragma unroll
        for (int j = 0; j < 8; ++j) {
            acc[j]     += ap * (float)v0[j];
            acc[8 + j] += ap * (float)v1[j];
        }
    }

    const int obase = b * 256 + g * 64 + c * 16;
    const int off = h * 64 + w;
    #pragma unroll
    for (int dd = 0; dd < 16; ++dd)
        out[(size_t)(obase + dd) * HWSZ + off] = acc[dd];
}

extern "C" void kernel_launch(void* const* d_in, const int* in_sizes, int n_in,
                              void* d_out, int out_size, void* d_ws, size_t ws_size,
                              hipStream_t stream) {
    const float* x  = (const float*)d_in[0];
    const float* wq = (const float*)d_in[1];
    const float* bq = (const float*)d_in[2];
    const float* wk = (const float*)d_in[3];
    const float* bk = (const float*)d_in[4];
    const float* wv = (const float*)d_in[5];
    const float* bv = (const float*)d_in[6];
    float* out = (float*)d_out;

    char* ws = (char*)d_ws;
    _Float16* qh = (_Float16*)ws;                      //  8.39 MB
    _Float16* kh = (_Float16*)(ws + 8388608);          //  8.39 MB
    _Float16* vh = (_Float16*)(ws + 16777216);         //  8.39 MB

    qkv_gemm_kernel<<<dim3(768), 512, 0, stream>>>(x, wq, bq, wk, bk, wv, bv,
                                                   qh, kh, vh);
    loc_attn_kernel<<<dim3(1024), 256, 0, stream>>>(qh, kh, vh, out);
}

// Round 16
// 33.610 us; speedup vs baseline: 1.2937x; 1.1108x over previous
//
#include <hip/hip_runtime.h>
#include <cstddef>
#include <cstdint>

#define BDIM 4
#define HH   64
#define WW   64
#define NG   4
#define GD   64
#define HWSZ 4096
#define NTOT 16384          // BDIM*HWSZ
#define CIN  256

typedef __attribute__((ext_vector_type(4))) float f32x4;
typedef _Float16 f16x4_t __attribute__((ext_vector_type(4)));
typedef _Float16 f16x8_t __attribute__((ext_vector_type(8)));

__device__ __forceinline__ void lds_load16(const void* g, void* l) {
    __builtin_amdgcn_global_load_lds(
        (const __attribute__((address_space(1))) unsigned int*)g,
        (__attribute__((address_space(3))) unsigned int*)l, 16, 0, 0);
}

// ---------- fused QKV GEMM: fp32 in, fp16 MFMA, fp16 blocked out ----------
// D[768 x 16384] = W[768 x 256] * x[256 x 16384]. 128x128 tile, 4 waves,
// BK=32, 8 K-steps, 2-deep double buffer (issue-early / write-late).
//   A (W): gload_lds fp32, 16B k-block swizzle kb^=(m&7); frags 2xb128+cvt.
//   B (x): reg-staged transpose -> Bs[px][32k] fp16; 16B slot swizzle
//          slot = ko ^ (px&3) on BOTH ds_write and ds_read; frags 1xb128.
// Best measured config of the session (R12: 33.8 us total).
__global__ __launch_bounds__(256, 3) void qkv_gemm_kernel(
    const float* __restrict__ x,
    const float* __restrict__ wq, const float* __restrict__ bq,
    const float* __restrict__ wk, const float* __restrict__ bk,
    const float* __restrict__ wv, const float* __restrict__ bv,
    _Float16* __restrict__ qh, _Float16* __restrict__ kh,
    _Float16* __restrict__ vh)
{
    __shared__ float    As[2][128 * 32];   // 2 x 16 KB fp32
    __shared__ _Float16 Bs[2][128 * 32];   // 2 x  8 KB fp16

    const int t  = threadIdx.x;
    const int bx = blockIdx.x;
    const int u  = (bx & 7) * 96 + (bx >> 3);   // XCD-chunked (768 = 8*96)
    const int mt = u % 6;                       // consecutive u share nt (x panel)
    const int nt = u / 6;                       // 0..127

    const int l     = t & 63;
    const int wid   = t >> 6;
    const int wm    = wid >> 1, wn = wid & 1;
    const int lrow  = l & 15;
    const int grp   = l >> 4;                   // koct 0..3
    const int lrow4 = grp * 4;

    const float* wsel = (mt < 2) ? wq : (mt < 4) ? wk : wv;
    const float* bsel = (mt < 2) ? bq : (mt < 4) ? bk : bv;
    _Float16*    osel = (mt < 2) ? qh : (mt < 4) ? kh : vh;
    const int    mtl  = mt & 1;

    const int bi  = nt >> 5;
    const int px0 = (nt & 31) * 128;

    // acc init with bias
    f32x4 acc[4][4];
    #pragma unroll
    for (int mi = 0; mi < 4; ++mi) {
        const f32x4 bb = *(const f32x4*)&bsel[mtl * 128 + wm * 64 + mi * 16 + lrow4];
        #pragma unroll
        for (int ni = 0; ni < 4; ++ni) acc[mi][ni] = bb;
    }

    // ---- A staging sources (4 x 16B gload_lds per step; swizzled source) ----
    const float* asrc[4];
    #pragma unroll
    for (int i = 0; i < 4; ++i) {
        const int w16 = i * 256 + t;
        const int m  = w16 >> 3;
        const int kb = w16 & 7;
        asrc[i] = wsel + (size_t)(mtl * 128 + m) * CIN + ((kb ^ (m & 7)) * 4);
    }

    // ---- B staging: px = t&127, kocts {t>>7, (t>>7)+2} ----
    const int spx  = t & 127;
    const int sko0 = t >> 7;                 // 0..1
    const float* xbp = x + (size_t)bi * CIN * HWSZ + px0 + spx;
    const int bw0 = spx * 32 + ((sko0       ^ (spx & 3)) * 8);
    const int bw1 = spx * 32 + (((sko0 + 2) ^ (spx & 3)) * 8);

    // ---- prologue: stage kt=0 into buf 0 ----
    {
        #pragma unroll
        for (int i = 0; i < 4; ++i)
            lds_load16(asrc[i], &As[0][(i * 256 + t) * 4]);
        float r0[8], r1[8];
        #pragma unroll
        for (int j = 0; j < 8; ++j) r0[j] = xbp[(size_t)(sko0 * 8 + j) * HWSZ];
        #pragma unroll
        for (int j = 0; j < 8; ++j) r1[j] = xbp[(size_t)((sko0 + 2) * 8 + j) * HWSZ];
        f16x8_t w0, w1;
        #pragma unroll
        for (int j = 0; j < 8; ++j) { w0[j] = (_Float16)r0[j]; w1[j] = (_Float16)r1[j]; }
        *(f16x8_t*)&Bs[0][bw0] = w0;
        *(f16x8_t*)&Bs[0][bw1] = w1;
        __syncthreads();
    }

    for (int kt = 0; kt < 8; ++kt) {
        const int cur = kt & 1, nxt = cur ^ 1;

        // issue next-step loads early (hide under frag reads + MFMA)
        float r0[8], r1[8];
        if (kt < 7) {
            const int kb = (kt + 1) * 32;
            #pragma unroll
            for (int i = 0; i < 4; ++i)
                lds_load16(asrc[i] + kb, &As[nxt][(i * 256 + t) * 4]);
            #pragma unroll
            for (int j = 0; j < 8; ++j) r0[j] = xbp[(size_t)(kb + sko0 * 8 + j) * HWSZ];
            #pragma unroll
            for (int j = 0; j < 8; ++j) r1[j] = xbp[(size_t)(kb + (sko0 + 2) * 8 + j) * HWSZ];
        }

        // A fragments: 2 swizzled b128 fp32 reads + cvt
        f16x8_t af[4];
        #pragma unroll
        for (int mi = 0; mi < 4; ++mi) {
            const int m = wm * 64 + mi * 16 + lrow;
            const int s = m & 7;
            const f32x4 a0 = *(const f32x4*)&As[cur][m * 32 + ((2 * grp) ^ s) * 4];
            const f32x4 a1 = *(const f32x4*)&As[cur][m * 32 + ((2 * grp + 1) ^ s) * 4];
            f16x8_t f;
            #pragma unroll
            for (int j = 0; j < 4; ++j) { f[j] = (_Float16)a0[j]; f[4 + j] = (_Float16)a1[j]; }
            af[mi] = f;
        }
        // B fragments: single swizzled b128 fp16 read
        f16x8_t bf[4];
        #pragma unroll
        for (int ni = 0; ni < 4; ++ni) {
            const int px = wn * 64 + ni * 16 + lrow;
            bf[ni] = *(const f16x8_t*)&Bs[cur][px * 32 + ((grp ^ (px & 3)) * 8)];
        }
        #pragma unroll
        for (int mi = 0; mi < 4; ++mi)
            #pragma unroll
            for (int ni = 0; ni < 4; ++ni)
                acc[mi][ni] = __builtin_amdgcn_mfma_f32_16x16x32_f16(
                    af[mi], bf[ni], acc[mi][ni], 0, 0, 0);

        // write-late: convert + store next B tile
        if (kt < 7) {
            f16x8_t w0, w1;
            #pragma unroll
            for (int j = 0; j < 8; ++j) { w0[j] = (_Float16)r0[j]; w1[j] = (_Float16)r1[j]; }
            *(f16x8_t*)&Bs[nxt][bw0] = w0;
            *(f16x8_t*)&Bs[nxt][bw1] = w1;
        }
        __syncthreads();
    }

    // epilogue: D row (m) = grp*4+reg, col (n) = l&15 — blocked fp16 stores
    #pragma unroll
    for (int ni = 0; ni < 4; ++ni) {
        const size_t ng = (size_t)(nt * 128 + wn * 64 + ni * 16 + lrow);
        #pragma unroll
        for (int mi = 0; mi < 4; ++mi) {
            f16x4_t hv;
            #pragma unroll
            for (int j = 0; j < 4; ++j) hv[j] = (_Float16)acc[mi][ni][j];
            const int chunk = mtl * 8 + wm * 4 + mi;     // 0..15
            *(f16x4_t*)&osel[((size_t)chunk * NTOT + ng) * 16 + lrow4] = hv;
        }
    }
}

// ---------- local grouped attention: q,k,v fp16 blocked; fp32 math ----------
__global__ __launch_bounds__(256) void loc_attn_kernel(
    const _Float16* __restrict__ qh, const _Float16* __restrict__ kh,
    const _Float16* __restrict__ vh, float* __restrict__ out)
{
    const int t   = threadIdx.x;
    const int bx0 = blockIdx.x;
    const int bx  = (bx0 & 7) * 128 + (bx0 >> 3);
    const int h = bx & 63;
    const int g = (bx >> 6) & 3;
    const int b = bx >> 8;

    const int wl  = t & 15;
    const int c   = (t >> 4) & 3;
    const int wid = t >> 6;
    const int w   = wid * 16 + wl;

    const int ck = g * 4 + c;                    // chunk index 0..15
    const size_t n = (size_t)b * HWSZ + h * 64 + w;

    float qf[16];
    {
        const _Float16* qp = &qh[((size_t)ck * NTOT + n) * 16];
        const f16x8_t q0 = *(const f16x8_t*)qp;
        const f16x8_t q1 = *(const f16x8_t*)(qp + 8);
        #pragma unroll
        for (int j = 0; j < 8; ++j) { qf[j] = (float)q0[j]; qf[8 + j] = (float)q1[j]; }
    }

    float logit[9];
    #pragma unroll
    for (int p = 0; p < 9; ++p) {
        const int dh = p / 3 - 1, dw = p % 3 - 1;
        const int hh = h + dh, ww2 = w + dw;
        float part = 0.f;
        if (hh >= 0 && hh < HH && ww2 >= 0 && ww2 < WW) {
            const size_t nn = (size_t)b * HWSZ + hh * 64 + ww2;
            const _Float16* kp = &kh[((size_t)ck * NTOT + nn) * 16];
            const f16x8_t k0 = *(const f16x8_t*)kp;
            const f16x8_t k1 = *(const f16x8_t*)(kp + 8);
            #pragma unroll
            for (int j = 0; j < 8; ++j)
                part += qf[j] * (float)k0[j] + qf[8 + j] * (float)k1[j];
        }
        part += __shfl_xor(part, 16, 64);
        part += __shfl_xor(part, 32, 64);
        logit[p] = part;
    }

    float mx = logit[0];
    #pragma unroll
    for (int p = 1; p < 9; ++p) mx = fmaxf(mx, logit[p]);
    float a[9];
    float s = 0.f;
    #pragma unroll
    for (int p = 0; p < 9; ++p) { a[p] = __expf(logit[p] - mx); s += a[p]; }
    const float inv = 1.f / s;
    #pragma unroll
    for (int p = 0; p < 9; ++p) a[p] *= inv;

    float acc[16];
    #pragma unroll
    for (int dd = 0; dd < 16; ++dd) acc[dd] = 0.f;
    #pragma unroll
    for (int p = 0; p < 9; ++p) {
        const int dh = p / 3 - 1, dw = p % 3 - 1;
        const int hh = h + dh, ww2 = w + dw;
        if (hh < 0 || hh >= HH || ww2 < 0 || ww2 >= WW) continue;
        const size_t nn = (size_t)b * HWSZ + hh * 64 + ww2;
        const _Float16* vp = &vh[((size_t)ck * NTOT + nn) * 16];
        const f16x8_t v0 = *(const f16x8_t*)vp;
        const f16x8_t v1 = *(const f16x8_t*)(vp + 8);
        const float ap = a[p];
        #pragma unroll
        for (int j = 0; j < 8; ++j) {
            acc[j]     += ap * (float)v0[j];
            acc[8 + j] += ap * (float)v1[j];
        }
    }

    const int obase = b * 256 + g * 64 + c * 16;
    const int off = h * 64 + w;
    #pragma unroll
    for (int dd = 0; dd < 16; ++dd)
        out[(size_t)(obase + dd) * HWSZ + off] = acc[dd];
}

extern "C" void kernel_launch(void* const* d_in, const int* in_sizes, int n_in,
                              void* d_out, int out_size, void* d_ws, size_t ws_size,
                              hipStream_t stream) {
    const float* x  = (const float*)d_in[0];
    const float* wq = (const float*)d_in[1];
    const float* bq = (const float*)d_in[2];
    const float* wk = (const float*)d_in[3];
    const float* bk = (const float*)d_in[4];
    const float* wv = (const float*)d_in[5];
    const float* bv = (const float*)d_in[6];
    float* out = (float*)d_out;

    char* ws = (char*)d_ws;
    _Float16* qh = (_Float16*)ws;                      //  8.39 MB
    _Float16* kh = (_Float16*)(ws + 8388608);          //  8.39 MB
    _Float16* vh = (_Float16*)(ws + 16777216);         //  8.39 MB

    qkv_gemm_kernel<<<dim3(768), 256, 0, stream>>>(x, wq, bq, wk, bk, wv, bv,
                                                   qh, kh, vh);
    loc_attn_kernel<<<dim3(1024), 256, 0, stream>>>(qh, kh, vh, out);
}